// Round 12
// baseline (183.765 us; speedup 1.0000x reference)
//
#include <hip/hip_runtime.h>

typedef _Float16 f16x8 __attribute__((ext_vector_type(8)));  // 8 f16 (4 VGPR) MFMA frag
typedef float f32x4 __attribute__((ext_vector_type(4)));     // MFMA C/D frag

#define CCH 64
#define KCB 1024
#define HWSZ 4096
#define CHW 262144            // C*H*W
#define NXQ 4194304           // B*C*H*W
#define NMEAN 4194304.0       // N*C
#define PLANE_BYTES 131072    // 1024 codes * 64 ch * 2B
#define INV2048 0.00048828125f

// ---------------------------------------------------------------------------
// Kernel 1 (8192 thr): pack -2*E into TWO f16 planes (h, l'=2^11*residual)
// in MFMA-B frag order; e2[k]=||E[k]||^2; zero loss. Plane entry
// gid=(ntile*2+ks)*64+l holds code col=(l&15), channels c=ks*32+(l>>4)*8+j.
// f16 split-2 validated in HW (r11 passed, absmax 2^-9, no index flips).
// ---------------------------------------------------------------------------
__global__ void vq_prep(const float* __restrict__ E, float* __restrict__ e2,
                        f16x8* __restrict__ Bh, f16x8* __restrict__ Bl,
                        double* __restrict__ loss_acc) {
    int gid = blockIdx.x * blockDim.x + threadIdx.x;   // 0..8191
    if (gid == 0) *loss_acc = 0.0;
    {
        int nt = gid >> 7, rem = gid & 127;
        int ks = rem >> 6, l = rem & 63;
        int code = nt * 16 + (l & 15);
        int cb   = ks * 32 + ((l >> 4) << 3);
        const float* ep = E + code * CCH + cb;
        f16x8 vh, vl;
#pragma unroll
        for (int j = 0; j < 8; ++j) {
            float v = -2.f * ep[j];                    // exact scaling
            _Float16 h = (_Float16)v;                  // RNE
            float r = v - (float)h;                    // exact residual
            vh[j] = h;
            vl[j] = (_Float16)(r * 2048.0f);           // scaled -> normal f16
        }
        Bh[gid] = vh; Bl[gid] = vl;
    }
    if (gid < KCB) {
        const float4* e4 = reinterpret_cast<const float4*>(E + gid * CCH);
        float s = 0.f;
#pragma unroll
        for (int i = 0; i < 16; ++i) {
            float4 v = e4[i];
            s = fmaf(v.x, v.x, s); s = fmaf(v.y, v.y, s);
            s = fmaf(v.z, v.z, s); s = fmaf(v.w, v.w, s);
        }
        e2[gid] = s;
    }
}

// ---------------------------------------------------------------------------
// Kernel 2: MFMA VQ. 1024 WGs x 256 thr (4 waves). WG owns 64 tokens.
//   Wave w scans K-slice [w*256,(w+1)*256) in 8 chunks of 32 — waves are
//   INDEPENDENT (zero main-loop barriers, r9 lesson); 2 waves/SIMD at
//   ~200 VGPR so residual stalls overlap another wave's MFMAs (r11 fix:
//   1 wave/SIMD exposed every L2 latency serially).
//   Prefetch is a STATIC PING-PONG over named buffers P/Q — no guard, no
//   rotation copies — so the compiler cannot sink the loads to their use
//   (r11's VGPR=120 proved if(ch<31)+copies got sunk). e2 seeds hoisted.
//   Math bit-identical to the r11-validated run: 3 f16 MFMA passes,
//   s = (e2 + h*h) + (h*l'+l'*h)/2048; argmin ch,nt asc, strict <,
//   lower-k shfl ties; cross-wave combine in ascending w (= ascending k).
// ---------------------------------------------------------------------------
__global__ __launch_bounds__(256, 2) void vq_main(
    const float* __restrict__ x, const float* __restrict__ E,
    const f16x8* __restrict__ Bh, const f16x8* __restrict__ Bl,
    const float* __restrict__ e2, float* __restrict__ out,
    double* __restrict__ loss_acc)
{
    __shared__ float XSL[64];
    __shared__ float SB[4][64];
    __shared__ int   SI[4][64];

    const int t    = threadIdx.x;
    const int lane = t & 63;
    const int w    = t >> 6;               // K-slice id 0..3
    const int g    = lane >> 4;
    const int c15  = lane & 15;
    const int n0   = blockIdx.x * 64;
    const int b    = n0 >> 12;             // 64 | 4096: constant per block
    const int hw0  = n0 & 4095;

    // ---- A-frags [mt][ks]: all 64 tokens, per wave (x is L1/L2-hot) ----
    f16x8 ah[4][2], al[4][2];
#pragma unroll
    for (int mt = 0; mt < 4; ++mt) {
        const float* xp = x + b * CHW + hw0 + mt * 16 + c15;
        float xs = 0.f;
#pragma unroll
        for (int ks = 0; ks < 2; ++ks)
#pragma unroll
            for (int j = 0; j < 8; ++j) {
                float v = xp[(ks * 32 + g * 8 + j) * HWSZ];
                xs = fmaf(v, v, xs);
                _Float16 h = (_Float16)v;
                float r = v - (float)h;
                ah[mt][ks][j] = h;
                al[mt][ks][j] = (_Float16)(r * 2048.0f);
            }
        xs += __shfl_xor(xs, 16, 64);      // fold 4 k-groups -> full ||x||^2
        xs += __shfl_xor(xs, 32, 64);
        if (w == 0 && lane < 16) XSL[mt * 16 + lane] = xs;
    }

    // ---- hoist e2 seeds for this wave's 256-code slice (16 VGPR) ----
    float e2w[16];
#pragma unroll
    for (int i = 0; i < 16; ++i) e2w[i] = e2[w * 256 + i * 16 + c15];

    float best[4][4]; int bidx[4][4];
#pragma unroll
    for (int mt = 0; mt < 4; ++mt)
#pragma unroll
        for (int r = 0; r < 4; ++r) { best[mt][r] = 3.4e38f; bidx[mt][r] = 0; }

    // ping-pong buffers (named => static indexing, rule #20)
    f16x8 pbh[2][2], pbl[2][2], qbh[2][2], qbl[2][2];

#define LOADB(BH, BL, c) do {                                               \
    _Pragma("unroll")                                                       \
    for (int nt_ = 0; nt_ < 2; ++nt_) {                                     \
        _Pragma("unroll")                                                   \
        for (int ks_ = 0; ks_ < 2; ++ks_) {                                 \
            int idx_ = (((w * 16 + (c) * 2 + nt_) * 2) + ks_) * 64 + lane;  \
            BH[nt_][ks_] = Bh[idx_];                                        \
            BL[nt_][ks_] = Bl[idx_];                                        \
        }                                                                   \
    } } while (0)

#define COMPUTE(BH, BL, c) do {                                             \
    _Pragma("unroll")                                                       \
    for (int nt_ = 0; nt_ < 2; ++nt_) {                                     \
        const float s0_ = e2w[(c) * 2 + nt_];                               \
        const int   k_  = w * 256 + (c) * 32 + nt_ * 16 + c15;              \
        _Pragma("unroll")                                                   \
        for (int mt_ = 0; mt_ < 4; ++mt_) {                                 \
            f32x4 a0_ = (f32x4){s0_, s0_, s0_, s0_};                        \
            f32x4 a1_ = (f32x4){0.f, 0.f, 0.f, 0.f};                        \
            _Pragma("unroll")                                               \
            for (int ks_ = 0; ks_ < 2; ++ks_) {                             \
                a0_ = __builtin_amdgcn_mfma_f32_16x16x32_f16(ah[mt_][ks_], BH[nt_][ks_], a0_, 0, 0, 0); \
                a1_ = __builtin_amdgcn_mfma_f32_16x16x32_f16(ah[mt_][ks_], BL[nt_][ks_], a1_, 0, 0, 0); \
                a1_ = __builtin_amdgcn_mfma_f32_16x16x32_f16(al[mt_][ks_], BH[nt_][ks_], a1_, 0, 0, 0); \
            }                                                               \
            _Pragma("unroll")                                               \
            for (int r_ = 0; r_ < 4; ++r_) {                                \
                float s_ = fmaf(a1_[r_], INV2048, a0_[r_]);                 \
                if (s_ < best[mt_][r_]) { best[mt_][r_] = s_; bidx[mt_][r_] = k_; } \
            }                                                               \
        }                                                                   \
    } } while (0)

    // ---- static ping-pong pipeline over 8 chunks: loads issue a full
    //      MFMA-chunk (~930 cyc) ahead of their waitcnt ----
    LOADB(pbh, pbl, 0);
#pragma unroll 1
    for (int ii = 0; ii < 3; ++ii) {
        const int c0 = 2 * ii;
        LOADB(qbh, qbl, c0 + 1);
        COMPUTE(pbh, pbl, c0);
        LOADB(pbh, pbl, c0 + 2);
        COMPUTE(qbh, qbl, c0 + 1);
    }
    LOADB(qbh, qbl, 7);
    COMPUTE(pbh, pbl, 6);
    COMPUTE(qbh, qbl, 7);

#undef LOADB
#undef COMPUTE

    // ---- per-wave argmin reduce over 16 code-cols (tie -> lower k) ----
#pragma unroll
    for (int mt = 0; mt < 4; ++mt)
#pragma unroll
        for (int r = 0; r < 4; ++r) {
            float v = best[mt][r]; int k = bidx[mt][r];
#pragma unroll
            for (int off = 1; off < 16; off <<= 1) {
                float ov = __shfl_xor(v, off, 64);
                int   ok = __shfl_xor(k, off, 64);
                if (ov < v || (ov == v && ok < k)) { v = ov; k = ok; }
            }
            if (c15 == 0) {                // token row = g*4 + r (m89 map)
                SB[w][mt * 16 + g * 4 + r] = v;
                SI[w][mt * 16 + g * 4 + r] = k;
            }
        }
    __syncthreads();

    // ---- every wave combines (asc w = asc k); epilogue split by wave ----
    {
        float bv = SB[0][lane]; int bi = SI[0][lane];
#pragma unroll
        for (int ww = 1; ww < 4; ++ww) {
            float v = SB[ww][lane];
            if (v < bv) { bv = v; bi = SI[ww][lane]; }
        }

        // wave w writes x_q channels [w*16, (w+1)*16) for token n0+lane
        const float4* eq = reinterpret_cast<const float4*>(E + bi * CCH + w * 16);
        float4 q0 = eq[0], q1 = eq[1], q2 = eq[2], q3 = eq[3];
        float* oq = out + b * CHW + (w * 16) * HWSZ + hw0 + lane;
        oq[0 * HWSZ]  = q0.x; oq[1 * HWSZ]  = q0.y; oq[2 * HWSZ]  = q0.z; oq[3 * HWSZ]  = q0.w;
        oq[4 * HWSZ]  = q1.x; oq[5 * HWSZ]  = q1.y; oq[6 * HWSZ]  = q1.z; oq[7 * HWSZ]  = q1.w;
        oq[8 * HWSZ]  = q2.x; oq[9 * HWSZ]  = q2.y; oq[10 * HWSZ] = q2.z; oq[11 * HWSZ] = q2.w;
        oq[12 * HWSZ] = q3.x; oq[13 * HWSZ] = q3.y; oq[14 * HWSZ] = q3.z; oq[15 * HWSZ] = q3.w;

        if (w == 0) {                      // indices + fused loss
            out[NXQ + 2 + n0 + lane] = (float)bi;
            float lsum = bv + XSL[lane];   // ||x-q||^2
#pragma unroll
            for (int off = 32; off > 0; off >>= 1)
                lsum += __shfl_xor(lsum, off, 64);
            if (lane == 0) atomicAdd(loss_acc, (double)lsum);
        }
    }
}

// ---------------------------------------------------------------------------
// Kernel 3: finalize both loss scalars (forward values identical).
// ---------------------------------------------------------------------------
__global__ void vq_final(const double* __restrict__ loss_acc,
                         float* __restrict__ out) {
    if (threadIdx.x == 0) {
        float m = (float)(*loss_acc / NMEAN);
        out[NXQ]     = m;
        out[NXQ + 1] = m;
    }
}

// ---------------------------------------------------------------------------
extern "C" void kernel_launch(void* const* d_in, const int* in_sizes, int n_in,
                              void* d_out, int out_size, void* d_ws, size_t ws_size,
                              hipStream_t stream) {
    const float* x = (const float*)d_in[0];          // [16,64,64,64] f32
    const float* E = (const float*)d_in[1];          // [1024,64] f32
    float* out = (float*)d_out;                      // [x_q | cb | cm | idx]
    double* loss_acc = (double*)d_ws;                // 8 B
    float*  e2 = (float*)((char*)d_ws + 64);         // 4 KB
    f16x8*  Bh = (f16x8*)((char*)d_ws + 8192);       // 128 KB
    f16x8*  Bl = (f16x8*)((char*)d_ws + 8192 + PLANE_BYTES);

    vq_prep <<<128,  64,  0, stream>>>(E, e2, Bh, Bl, loss_acc);
    vq_main <<<1024, 256, 0, stream>>>(x, E, Bh, Bl, e2, out, loss_acc);
    vq_final<<<1,    64,  0, stream>>>(loss_acc, out);
}